// Round 17
// baseline (202.306 us; speedup 1.0000x reference)
//
#include <hip/hip_runtime.h>
#include <hip/hip_bf16.h>

#define NB 4
#define NS 2048
#define ND 1024
#define NH 16
#define HDIM 64
#define NM (NB * NS)
#define MN_FULL ((size_t)NM * ND)

typedef short short8 __attribute__((ext_vector_type(8)));
typedef float f32x4 __attribute__((ext_vector_type(4)));
typedef float f32x16 __attribute__((ext_vector_type(16)));
typedef unsigned uint4v __attribute__((ext_vector_type(4)));

__device__ __forceinline__ short bf16rne(float f) {
    unsigned u = __builtin_bit_cast(unsigned, f);
    u += 0x7fff + ((u >> 16) & 1);
    return (short)(u >> 16);
}
__device__ __forceinline__ float bf2f(short s) {
    unsigned u = ((unsigned)(unsigned short)s) << 16;
    return __builtin_bit_cast(float, u);
}
__device__ __forceinline__ void gl_lds16(const short* g, short* l) {
    __builtin_amdgcn_global_load_lds(
        (const __attribute__((address_space(1))) void*)g,
        (__attribute__((address_space(3))) void*)l, 16, 0, 0);
}
__device__ __forceinline__ float fexp2(float x) {
#if __has_builtin(__builtin_amdgcn_exp2f)
    return __builtin_amdgcn_exp2f(x);
#else
    return exp2f(x);
#endif
}
__device__ __forceinline__ unsigned cvtpk(float a, float b) {
    unsigned d;
    asm("v_cvt_pk_bf16_f32 %0, %1, %2" : "=v"(d) : "v"(a), "v"(b));
    return d;
}
__device__ __forceinline__ void plswap(unsigned& x, unsigned& y) {
    asm("v_permlane32_swap_b32 %0, %1" : "+v"(x), "+v"(y));
}
__device__ __forceinline__ short8 mk8(unsigned a, unsigned b, unsigned c, unsigned d) {
    uint4v u = {a, b, c, d};
    return __builtin_bit_cast(short8, u);
}
__device__ __forceinline__ short8 cvt8(const float* s) {
    float4 x0 = *(const float4*)s;
    float4 x1 = *(const float4*)(s + 4);
    uint4v u = {cvtpk(x0.x, x0.y), cvtpk(x0.z, x0.w),
                cvtpk(x1.x, x1.y), cvtpk(x1.z, x1.w)};
    return __builtin_bit_cast(short8, u);
}

// ---------------------------------------------------------------------------
// convW4: 4 weights f32 W[k][n] -> W^T bf16 [n][k], swizzled by (n&7).
// ---------------------------------------------------------------------------
__global__ __launch_bounds__(256)
void convW4(const float* __restrict__ W0, const float* __restrict__ W1,
            const float* __restrict__ W2, const float* __restrict__ W3,
            short* __restrict__ Wb)
{
    const int z = blockIdx.z;
    const float* W = (z == 0) ? W0 : (z == 1) ? W1 : (z == 2) ? W2 : W3;
    short* Wh = Wb + (size_t)z * ND * ND;

    const int idx = blockIdx.x * 256 + threadIdx.x;
    const int n = idx & 1023;
    const int k = (idx >> 10) << 3;
    short8 hv;
#pragma unroll
    for (int j = 0; j < 8; ++j) hv[j] = bf16rne(W[(size_t)(k + j) * ND + n]);
    const int ksw = (k & ~63) | ((k & 63) ^ ((n & 7) << 3));
    *(short8*)(Wh + ((size_t)n << 10) + ksw) = hv;
}

// ---------------------------------------------------------------------------
// MFMA GEMM with optional fused f32->bf16 staging (cvt_pk + swizzled ds_write;
// rounding bitwise-identical to the old convA). bf16 operands use gl_lds with
// pre-swizzled source data. D[row][col] = sum_k A[row][k]*B[col][k].
// EPI 0: f32 out. EPI 3: bf16 out (scale). EPI 2: VT out.
// ---------------------------------------------------------------------------
template <int EPI, bool AF32, bool BF32>
__global__ __launch_bounds__(256, 3)
void gemm2(const void* __restrict__ Ap, const void* __restrict__ Bp,
           short* __restrict__ D1, float* __restrict__ Cf, float scale)
{
    __shared__ short lds[16384];
    short* AhS = lds;
    short* BhS = lds + 8192;

    const int t = threadIdx.x, w = t >> 6, l = t & 63;
    const int g = l >> 4, li = l & 15;
    const int wr = w >> 1, wc = w & 1;
    const size_t bm = (size_t)blockIdx.x * 128, bn = (size_t)blockIdx.y * 128;

    f32x4 acc[4][4];
#pragma unroll
    for (int i = 0; i < 4; ++i)
#pragma unroll
        for (int j = 0; j < 4; ++j) acc[i][j] = (f32x4){0.f, 0.f, 0.f, 0.f};

    const int srow = w * 32 + (l >> 3);
    const int schk = (l & 7) << 3;
    const int lbase = w * 32 * 64;
    // explicit ds_write destination (swizzle on write addr; == gl_lds linear slot ^ swz)
    const int xdst = lbase + (l >> 3) * 64 + (schk ^ (((l >> 3) & 7) << 3));

    const short* pAh = nullptr; const float* pAf = nullptr;
    const short* pBh = nullptr; const float* pBf = nullptr;
    if constexpr (AF32) pAf = (const float*)Ap + (bm + srow) * 1024 + schk;
    else                pAh = (const short*)Ap + (bm + srow) * 1024 + schk;
    if constexpr (BF32) pBf = (const float*)Bp + (bn + srow) * 1024 + schk;
    else                pBh = (const short*)Bp + (bn + srow) * 1024 + schk;

    for (int kt = 0; kt < 16; ++kt) {
        const int k0 = kt * 64;
        __syncthreads();
#pragma unroll
        for (int r = 0; r < 4; ++r) {
            const int go = r * 8 * 1024 + k0;
            if constexpr (AF32) *(short8*)&AhS[xdst + r * 512] = cvt8(pAf + go);
            else                gl_lds16(pAh + go, AhS + lbase + r * 512);
            if constexpr (BF32) *(short8*)&BhS[xdst + r * 512] = cvt8(pBf + go);
            else                gl_lds16(pBh + go, BhS + lbase + r * 512);
        }
        __syncthreads();
#pragma unroll
        for (int ks = 0; ks < 2; ++ks) {
            short8 fah[4], fbh[4];
#pragma unroll
            for (int i = 0; i < 4; ++i) {
                const int m = wr * 64 + i * 16 + li;
                const int c = (ks * 32 + g * 8) ^ ((m & 7) << 3);
                fah[i] = *(const short8*)&AhS[m * 64 + c];
                const int n = wc * 64 + i * 16 + li;
                const int cn = (ks * 32 + g * 8) ^ ((n & 7) << 3);
                fbh[i] = *(const short8*)&BhS[n * 64 + cn];
            }
#pragma unroll
            for (int i = 0; i < 4; ++i)
#pragma unroll
                for (int j = 0; j < 4; ++j)
                    acc[i][j] = __builtin_amdgcn_mfma_f32_16x16x32_bf16(fah[i], fbh[j], acc[i][j], 0, 0, 0);
        }
    }

    __syncthreads();
    float* Ofs = (float*)lds + w * 2048;
#pragma unroll
    for (int half = 0; half < 2; ++half) {
#pragma unroll
        for (int i = 0; i < 4; ++i)
#pragma unroll
            for (int jj = 0; jj < 2; ++jj)
#pragma unroll
                for (int r = 0; r < 4; ++r)
                    Ofs[(i * 16 + g * 4 + r) * 32 + jj * 16 + li] = acc[i][half * 2 + jj][r];
        // same-wave in-order LDS: reads below see writes above
        if (EPI == 3) {
#pragma unroll
            for (int rr = 0; rr < 2; ++rr) {
                const int row = rr * 32 + (l >> 1);
                const int coff = (l & 1) * 16;
                const float* src = &Ofs[row * 32 + coff];
                short8 h0, h1;
#pragma unroll
                for (int jj = 0; jj < 8; ++jj) {
                    h0[jj] = bf16rne(src[jj] * scale);
                    h1[jj] = bf16rne(src[8 + jj] * scale);
                }
                const size_t rg = bm + wr * 64 + row;
                const size_t cg = bn + wc * 64 + half * 32 + coff;
                *(short8*)(D1 + rg * 1024 + cg)     = h0;
                *(short8*)(D1 + rg * 1024 + cg + 8) = h1;
            }
        } else if (EPI == 0) {
#pragma unroll
            for (int rr = 0; rr < 2; ++rr) {
                const int row = rr * 32 + (l >> 1);
                const int coff = (l & 1) * 16;
                const float* src = &Ofs[row * 32 + coff];
                const size_t rg = bm + wr * 64 + row;
                const size_t cg = bn + wc * 64 + half * 32 + coff;
#pragma unroll
                for (int q = 0; q < 4; ++q)
                    *(float4*)(Cf + rg * 1024 + cg + q * 4) = *(const float4*)(src + q * 4);
            }
        } else {   // EPI == 2: VT[b][h][d][s]
#pragma unroll
            for (int p = 0; p < 4; ++p) {
                const int nl = p * 16 + (l >> 2);
                const int mc = (l & 3) * 8;
                const float* src = &Ofs[nl * 32 + mc];
                short8 v;
#pragma unroll
                for (int jj = 0; jj < 8; ++jj) v[jj] = bf16rne(src[jj]);
                const int ng = (int)bm + wr * 64 + nl;
                const size_t mg = bn + wc * 64 + half * 32 + mc;
                const int h_ = ng >> 6, d_ = ng & 63;
                const int b_ = (int)(mg >> 11), s_ = (int)(mg & 2047);
                *(short8*)(D1 + (((size_t)(b_ * NH + h_) * HDIM + d_) << 11) + s_) = v;
            }
        }
    }
}

// ---------------------------------------------------------------------------
// MFMA flash attention v11 (R16, proven: 76 us): K via gl_lds dbuf, V via
// reg-staging with write-addr swizzle, in-register P (cvt_pk + permlane),
// no max-tracking, masked-block fast path, XCD decode. grid=1024 x 256.
// ---------------------------------------------------------------------------
__global__ __launch_bounds__(256, 4)
void attn_mfma11(const short* __restrict__ Qh_g, const short* __restrict__ Kh_g,
                 const short* __restrict__ VT_g, const int* __restrict__ vlen_p,
                 short* __restrict__ AOh)
{
    __shared__ short smem[16384];   // Kb[2][4096] | Vb[2][4096]
    short* Kb = smem;
    short* Vb = smem + 8192;

    const int t = threadIdx.x, w = t >> 6, l = t & 63;
    const int lh = l >> 5, lq = l & 31;

    const int lin = blockIdx.x;
    const int pair = (lin & 7) * 8 + (lin >> 7);
    const int qt = (lin >> 3) & 15;
    const int hd = pair & 15, b = pair >> 4;
    const int q0 = qt * 128;
    const int vlen = vlen_p[b];

    const short* Vbh = VT_g + (size_t)((b * NH + hd) * HDIM) * NS;

    // ===== fast path: whole 128-row block masked -> out rows = mean(V) =====
    if (q0 >= vlen) {
        float* fs = (float*)smem;
        const int d = t & 63, pc = t >> 6;
        const short* vrow = Vbh + (size_t)d * NS + pc * 512;
        float s = 0.f;
#pragma unroll 8
        for (int c = 0; c < 64; ++c) {
            short8 v = *(const short8*)(vrow + c * 8);
            float ps = 0.f;
#pragma unroll
            for (int j = 0; j < 8; ++j) ps += bf2f(v[j]);
            s += ps;
        }
        fs[pc * 64 + d] = s;
        __syncthreads();
        float* mv = fs + 256;
        if (t < 64)
            mv[t] = (fs[t] + fs[64 + t] + fs[128 + t] + fs[192 + t]) * (1.0f / 2048.0f);
        __syncthreads();

        const int row = t >> 1, hf = t & 1;
        const size_t base = ((size_t)b * NS + q0 + row) * ND + hd * HDIM;
        const int swz = (row & 7) << 3;
#pragma unroll
        for (int ch = 0; ch < 4; ++ch) {
            const int c0 = hf * 32 + ch * 8;
            short8 hv;
#pragma unroll
            for (int j = 0; j < 8; ++j) hv[j] = bf16rne(mv[c0 + j]);
            *(short8*)(AOh + base + (c0 ^ swz)) = hv;
        }
        return;
    }

    // ===== normal path =====
    short8 qf[4];
    {
        const int qrow = q0 + w * 32 + lq;
        const size_t base = ((size_t)(b * NS) + qrow) * ND + hd * HDIM;
#pragma unroll
        for (int d = 0; d < 4; ++d)
            qf[d] = *(const short8*)(Qh_g + base + d * 16 + 8 * lh);
        if (qrow >= vlen) {
#pragma unroll
            for (int d = 0; d < 4; ++d)
#pragma unroll
                for (int j = 0; j < 8; ++j) qf[d][j] = 0;
        }
    }

    const int lrow = l >> 3, lcol = (l & 7) * 8;
    const int csw = lcol ^ (lrow << 3);
    const short* Ksrc = Kh_g + ((size_t)(b * NS) + w * 16 + lrow) * ND + hd * HDIM + csw;
    short* Kd = Kb + w * 16 * 64;

    const int vrow = w * 16 + lrow;
    const short* VsrcR = Vbh + (size_t)vrow * NS + lcol;
    const int vdst = vrow * 64 + (lcol ^ ((lrow & 7) << 3));

    float lsum = 0.f;
    f32x16 o0, o1;
#pragma unroll
    for (int i = 0; i < 16; ++i) { o0[i] = 0.f; o1[i] = 0.f; }

    gl_lds16(Ksrc, Kd);
    gl_lds16(Ksrc + 8 * ND, Kd + 512);
    {
        short8 a = *(const short8*)(VsrcR);
        short8 c = *(const short8*)(VsrcR + 8 * NS);
        *(short8*)&Vb[vdst] = a;
        *(short8*)&Vb[vdst + 512] = c;
    }

    const int r7s = (lq & 7) << 3;

    for (int kt = 0; kt < NS / 64; ++kt) {
        const int cur = kt & 1;
        __syncthreads();

        short8 vn0, vn1;
        const bool pf = (kt < NS / 64 - 1);
        if (pf) {
            const short* s_ = Ksrc + (size_t)(kt + 1) * 64 * ND;
            short* d_ = Kd + (cur ^ 1) * 4096;
            gl_lds16(s_, d_);
            gl_lds16(s_ + 8 * ND, d_ + 512);
            vn0 = *(const short8*)(VsrcR + (kt + 1) * 64);
            vn1 = *(const short8*)(VsrcR + (kt + 1) * 64 + 8 * NS);
        }

#pragma unroll
        for (int kb = 0; kb < 2; ++kb) {
            const int rbase = cur * 4096 + (kb * 32 + lq) * 64;
            short8 kf0 = *(const short8*)&Kb[rbase + ((0  + 8 * lh) ^ r7s)];
            short8 kf1 = *(const short8*)&Kb[rbase + ((16 + 8 * lh) ^ r7s)];
            short8 kf2 = *(const short8*)&Kb[rbase + ((32 + 8 * lh) ^ r7s)];
            short8 kf3 = *(const short8*)&Kb[rbase + ((48 + 8 * lh) ^ r7s)];

            const int vb0 = cur * 4096 + lq * 64;
            const int vb1 = cur * 4096 + (32 + lq) * 64;
            short8 v00 = *(const short8*)&Vb[vb0 + ((kb * 32 + 8 * lh) ^ r7s)];
            short8 v01 = *(const short8*)&Vb[vb0 + ((kb * 32 + 16 + 8 * lh) ^ r7s)];
            short8 v10 = *(const short8*)&Vb[vb1 + ((kb * 32 + 8 * lh) ^ r7s)];
            short8 v11 = *(const short8*)&Vb[vb1 + ((kb * 32 + 16 + 8 * lh) ^ r7s)];

            f32x16 acc;
#pragma unroll
            for (int i = 0; i < 16; ++i) acc[i] = 0.f;
            acc = __builtin_amdgcn_mfma_f32_32x32x16_bf16(kf0, qf[0], acc, 0, 0, 0);
            acc = __builtin_amdgcn_mfma_f32_32x32x16_bf16(kf1, qf[1], acc, 0, 0, 0);
            acc = __builtin_amdgcn_mfma_f32_32x32x16_bf16(kf2, qf[2], acc, 0, 0, 0);
            acc = __builtin_amdgcn_mfma_f32_32x32x16_bf16(kf3, qf[3], acc, 0, 0, 0);

            float e[16];
#pragma unroll
            for (int i = 0; i < 16; ++i) e[i] = fexp2(acc[i]);
            float s4 = 0.f;
#pragma unroll
            for (int i = 0; i < 16; ++i) s4 += e[i];
            lsum += s4;

            unsigned d0 = cvtpk(e[0],  e[1]);
            unsigned d1 = cvtpk(e[2],  e[3]);
            unsigned d2 = cvtpk(e[4],  e[5]);
            unsigned d3 = cvtpk(e[6],  e[7]);
            unsigned d4 = cvtpk(e[8],  e[9]);
            unsigned d5 = cvtpk(e[10], e[11]);
            unsigned d6 = cvtpk(e[12], e[13]);
            unsigned d7 = cvtpk(e[14], e[15]);
            plswap(d0, d2);
            plswap(d1, d3);
            plswap(d4, d6);
            plswap(d5, d7);
            short8 B0 = mk8(d0, d1, d2, d3);
            short8 B1 = mk8(d4, d5, d6, d7);

            o0 = __builtin_amdgcn_mfma_f32_32x32x16_bf16(v00, B0, o0, 0, 0, 0);
            o0 = __builtin_amdgcn_mfma_f32_32x32x16_bf16(v01, B1, o0, 0, 0, 0);
            o1 = __builtin_amdgcn_mfma_f32_32x32x16_bf16(v10, B0, o1, 0, 0, 0);
            o1 = __builtin_amdgcn_mfma_f32_32x32x16_bf16(v11, B1, o1, 0, 0, 0);
        }

        if (pf) {
            *(short8*)&Vb[(cur ^ 1) * 4096 + vdst]       = vn0;
            *(short8*)&Vb[(cur ^ 1) * 4096 + vdst + 512] = vn1;
        }
    }

    const float lt = lsum + __shfl_xor(lsum, 32);
    const float rin = 1.0f / lt;

    __syncthreads();
    float* Ob = (float*)smem + w * 1152;
    const int qe = l >> 1, dp = l & 1;
    const size_t aorow = (size_t)b * NS + q0 + w * 32 + qe;
    const int r7e = (qe & 7) << 3;
#pragma unroll
    for (int dt = 0; dt < 2; ++dt) {
        const f32x16 ov = dt ? o1 : o0;
#pragma unroll
        for (int r = 0; r < 16; ++r)
            Ob[lq * 36 + (r & 3) + 8 * (r >> 2) + 4 * lh] = ov[r] * rin;
        float xv[16];
#pragma unroll
        for (int c = 0; c < 4; ++c) {
            float4 x = *(const float4*)&Ob[qe * 36 + dp * 16 + c * 4];
            xv[c * 4 + 0] = x.x; xv[c * 4 + 1] = x.y;
            xv[c * 4 + 2] = x.z; xv[c * 4 + 3] = x.w;
        }
        short8 hv0, hv1;
#pragma unroll
        for (int j = 0; j < 8; ++j) {
            hv0[j] = bf16rne(xv[j]);
            hv1[j] = bf16rne(xv[8 + j]);
        }
        const size_t base = aorow * ND + hd * HDIM;
        *(short8*)(AOh + base + ((dt * 32 + dp * 16 + 0) ^ r7e)) = hv0;
        *(short8*)(AOh + base + ((dt * 32 + dp * 16 + 8) ^ r7e)) = hv1;
    }
}

// ---------------------------------------------------------------------------
extern "C" void kernel_launch(void* const* d_in, const int* in_sizes, int n_in,
                              void* d_out, int out_size, void* d_ws, size_t ws_size,
                              hipStream_t stream)
{
    const float* queries = (const float*)d_in[0];
    const float* keys    = (const float*)d_in[1];
    const float* values  = (const float*)d_in[2];
    const int*   vlen    = (const int*)d_in[3];
    const float* Wq      = (const float*)d_in[4];
    const float* Wk      = (const float*)d_in[5];
    const float* Wv      = (const float*)d_in[6];
    const float* Wo      = (const float*)d_in[7];
    float* out           = (float*)d_out;

    // ws: W4 (8MB) | Qhi | Khi | VT | AOh (4 x 16.8MB) = 75.2 MB
    short* W4  = (short*)d_ws;
    short* Qhi = W4 + 4 * (size_t)ND * ND;
    short* Khi = Qhi + MN_FULL;
    short* VT  = Khi + MN_FULL;
    short* AOh = VT + MN_FULL;

    const int gW = (int)((size_t)ND * ND / 8 / 256);  // 512
    dim3 gP(NM / 128, ND / 128);                      // (64, 8)
    dim3 gV(ND / 128, NM / 128);                      // (8, 64)

    const float QSCALE = 0.125f * 1.44269504089f;     // 1/sqrt(64) * log2(e)

    convW4<<<dim3(gW, 1, 4), 256, 0, stream>>>(Wq, Wk, Wv, Wo, W4);

    // fused f32->bf16 staging: activations read directly as f32
    gemm2<3, true, false><<<gP, 256, 0, stream>>>(queries, W4, Qhi, nullptr, QSCALE);
    gemm2<3, true, false><<<gP, 256, 0, stream>>>(keys, W4 + (size_t)ND * ND, Khi, nullptr, 1.0f);
    gemm2<2, false, true><<<gV, 256, 0, stream>>>(W4 + 2 * (size_t)ND * ND, values, VT, nullptr, 1.0f);

    attn_mfma11<<<dim3(1024), 256, 0, stream>>>(Qhi, Khi, VT, vlen, AOh);

    gemm2<0, false, false><<<gP, 256, 0, stream>>>(AOh, W4 + 3 * (size_t)ND * ND, nullptr, out, 1.0f);
}

// Round 18
// 198.730 us; speedup vs baseline: 1.0180x; 1.0180x over previous
//
#include <hip/hip_runtime.h>
#include <hip/hip_bf16.h>

#define NB 4
#define NS 2048
#define ND 1024
#define NH 16
#define HDIM 64
#define NM (NB * NS)
#define MN_FULL ((size_t)NM * ND)

typedef short short8 __attribute__((ext_vector_type(8)));
typedef float f32x4 __attribute__((ext_vector_type(4)));
typedef float f32x16 __attribute__((ext_vector_type(16)));
typedef unsigned uint4v __attribute__((ext_vector_type(4)));

__device__ __forceinline__ short bf16rne(float f) {
    unsigned u = __builtin_bit_cast(unsigned, f);
    u += 0x7fff + ((u >> 16) & 1);
    return (short)(u >> 16);
}
__device__ __forceinline__ float bf2f(short s) {
    unsigned u = ((unsigned)(unsigned short)s) << 16;
    return __builtin_bit_cast(float, u);
}
__device__ __forceinline__ void gl_lds16(const short* g, short* l) {
    __builtin_amdgcn_global_load_lds(
        (const __attribute__((address_space(1))) void*)g,
        (__attribute__((address_space(3))) void*)l, 16, 0, 0);
}
__device__ __forceinline__ float fexp2(float x) {
#if __has_builtin(__builtin_amdgcn_exp2f)
    return __builtin_amdgcn_exp2f(x);
#else
    return exp2f(x);
#endif
}
__device__ __forceinline__ unsigned cvtpk(float a, float b) {
    unsigned d;
    asm("v_cvt_pk_bf16_f32 %0, %1, %2" : "=v"(d) : "v"(a), "v"(b));
    return d;
}
__device__ __forceinline__ void plswap(unsigned& x, unsigned& y) {
    asm("v_permlane32_swap_b32 %0, %1" : "+v"(x), "+v"(y));
}
__device__ __forceinline__ short8 mk8(unsigned a, unsigned b, unsigned c, unsigned d) {
    uint4v u = {a, b, c, d};
    return __builtin_bit_cast(short8, u);
}

// ---------------------------------------------------------------------------
// convA3: 3 tensors f32 [M,1024] -> bf16 hi, swizzled in k-64 by (m&7).
// ---------------------------------------------------------------------------
__global__ __launch_bounds__(256)
void convA3(const float* __restrict__ A0, const float* __restrict__ A1,
            const float* __restrict__ A2, short* __restrict__ D0,
            short* __restrict__ D1, short* __restrict__ D2)
{
    const int z = blockIdx.z;
    const float* A = (z == 0) ? A0 : (z == 1) ? A1 : A2;
    short* D = (z == 0) ? D0 : (z == 1) ? D1 : D2;

    const size_t idx = (size_t)blockIdx.x * 256 + threadIdx.x;
    const int m = (int)(idx >> 7);
    const int k = (int)((idx & 127) << 3);
    const float* src = A + ((size_t)m << 10) + k;
    float4 x0 = *(const float4*)src;
    float4 x1 = *(const float4*)(src + 4);
    float xv[8] = {x0.x, x0.y, x0.z, x0.w, x1.x, x1.y, x1.z, x1.w};
    short8 hv;
#pragma unroll
    for (int j = 0; j < 8; ++j) hv[j] = bf16rne(xv[j]);
    const int ksw = (k & ~63) | ((k & 63) ^ ((m & 7) << 3));
    *(short8*)(D + ((size_t)m << 10) + ksw) = hv;
}

// ---------------------------------------------------------------------------
// convW4: 4 weights f32 W[k][n] -> W^T bf16 [n][k], swizzled by (n&7).
// ---------------------------------------------------------------------------
__global__ __launch_bounds__(256)
void convW4(const float* __restrict__ W0, const float* __restrict__ W1,
            const float* __restrict__ W2, const float* __restrict__ W3,
            short* __restrict__ Wb)
{
    const int z = blockIdx.z;
    const float* W = (z == 0) ? W0 : (z == 1) ? W1 : (z == 2) ? W2 : W3;
    short* Wh = Wb + (size_t)z * ND * ND;

    const int idx = blockIdx.x * 256 + threadIdx.x;
    const int n = idx & 1023;
    const int k = (idx >> 10) << 3;
    short8 hv;
#pragma unroll
    for (int j = 0; j < 8; ++j) hv[j] = bf16rne(W[(size_t)(k + j) * ND + n]);
    const int ksw = (k & ~63) | ((k & 63) ^ ((n & 7) << 3));
    *(short8*)(Wh + ((size_t)n << 10) + ksw) = hv;
}

// ---------------------------------------------------------------------------
// Single-bf16 MFMA GEMM (R16 proven): D[row][col] = sum_k A[row][k]*B[col][k].
// EPI 0: f32 out. EPI 3: bf16 out (scale). EPI 2: VT out.
// ---------------------------------------------------------------------------
template <int EPI>
__global__ __launch_bounds__(256, 3)
void gemm1(const short* __restrict__ Ah, const short* __restrict__ Bh,
           short* __restrict__ D1, float* __restrict__ Cf, float scale)
{
    __shared__ short lds[16384];
    short* AhS = lds;
    short* BhS = lds + 8192;

    const int t = threadIdx.x, w = t >> 6, l = t & 63;
    const int g = l >> 4, li = l & 15;
    const int wr = w >> 1, wc = w & 1;
    const size_t bm = (size_t)blockIdx.x * 128, bn = (size_t)blockIdx.y * 128;

    f32x4 acc[4][4];
#pragma unroll
    for (int i = 0; i < 4; ++i)
#pragma unroll
        for (int j = 0; j < 4; ++j) acc[i][j] = (f32x4){0.f, 0.f, 0.f, 0.f};

    const int srow = w * 32 + (l >> 3);
    const int schk = (l & 7) << 3;
    const short* pAh = Ah + (bm + srow) * 1024 + schk;
    const short* pBh = Bh + (bn + srow) * 1024 + schk;
    const int lbase = w * 32 * 64;

    for (int kt = 0; kt < 16; ++kt) {
        const int k0 = kt * 64;
        __syncthreads();
#pragma unroll
        for (int r = 0; r < 4; ++r) {
            const int go = r * 8 * 1024 + k0;
            const int lo_ = lbase + r * 512;
            gl_lds16(pAh + go, AhS + lo_);
            gl_lds16(pBh + go, BhS + lo_);
        }
        __syncthreads();
#pragma unroll
        for (int ks = 0; ks < 2; ++ks) {
            short8 fah[4], fbh[4];
#pragma unroll
            for (int i = 0; i < 4; ++i) {
                const int m = wr * 64 + i * 16 + li;
                const int c = (ks * 32 + g * 8) ^ ((m & 7) << 3);
                fah[i] = *(const short8*)&AhS[m * 64 + c];
                const int n = wc * 64 + i * 16 + li;
                const int cn = (ks * 32 + g * 8) ^ ((n & 7) << 3);
                fbh[i] = *(const short8*)&BhS[n * 64 + cn];
            }
#pragma unroll
            for (int i = 0; i < 4; ++i)
#pragma unroll
                for (int j = 0; j < 4; ++j)
                    acc[i][j] = __builtin_amdgcn_mfma_f32_16x16x32_bf16(fah[i], fbh[j], acc[i][j], 0, 0, 0);
        }
    }

    __syncthreads();
    float* Ofs = (float*)lds + w * 2048;
#pragma unroll
    for (int half = 0; half < 2; ++half) {
#pragma unroll
        for (int i = 0; i < 4; ++i)
#pragma unroll
            for (int jj = 0; jj < 2; ++jj)
#pragma unroll
                for (int r = 0; r < 4; ++r)
                    Ofs[(i * 16 + g * 4 + r) * 32 + jj * 16 + li] = acc[i][half * 2 + jj][r];
        // same-wave in-order LDS: reads below see writes above
        if (EPI == 3) {
#pragma unroll
            for (int rr = 0; rr < 2; ++rr) {
                const int row = rr * 32 + (l >> 1);
                const int coff = (l & 1) * 16;
                const float* src = &Ofs[row * 32 + coff];
                short8 h0, h1;
#pragma unroll
                for (int jj = 0; jj < 8; ++jj) {
                    h0[jj] = bf16rne(src[jj] * scale);
                    h1[jj] = bf16rne(src[8 + jj] * scale);
                }
                const size_t rg = bm + wr * 64 + row;
                const size_t cg = bn + wc * 64 + half * 32 + coff;
                *(short8*)(D1 + rg * 1024 + cg)     = h0;
                *(short8*)(D1 + rg * 1024 + cg + 8) = h1;
            }
        } else if (EPI == 0) {
#pragma unroll
            for (int rr = 0; rr < 2; ++rr) {
                const int row = rr * 32 + (l >> 1);
                const int coff = (l & 1) * 16;
                const float* src = &Ofs[row * 32 + coff];
                const size_t rg = bm + wr * 64 + row;
                const size_t cg = bn + wc * 64 + half * 32 + coff;
#pragma unroll
                for (int q = 0; q < 4; ++q)
                    *(float4*)(Cf + rg * 1024 + cg + q * 4) = *(const float4*)(src + q * 4);
            }
        } else {   // EPI == 2: VT[b][h][d][s]
#pragma unroll
            for (int p = 0; p < 4; ++p) {
                const int nl = p * 16 + (l >> 2);
                const int mc = (l & 3) * 8;
                const float* src = &Ofs[nl * 32 + mc];
                short8 v;
#pragma unroll
                for (int jj = 0; jj < 8; ++jj) v[jj] = bf16rne(src[jj]);
                const int ng = (int)bm + wr * 64 + nl;
                const size_t mg = bn + wc * 64 + half * 32 + mc;
                const int h_ = ng >> 6, d_ = ng & 63;
                const int b_ = (int)(mg >> 11), s_ = (int)(mg & 2047);
                *(short8*)(D1 + (((size_t)(b_ * NH + h_) * HDIM + d_) << 11) + s_) = v;
            }
        }
    }
}

// ---------------------------------------------------------------------------
// MFMA flash attention v12 = R16's proven v11 + s_setprio(1) around both
// MFMA clusters (T5; blocks are phase-independent so arbitration helps).
// K via gl_lds dbuf, V via reg-staging w/ write-addr swizzle, in-register P,
// no max-tracking, masked-block fast path, XCD decode. grid=1024 x 256.
// ---------------------------------------------------------------------------
__global__ __launch_bounds__(256, 4)
void attn_mfma12(const short* __restrict__ Qh_g, const short* __restrict__ Kh_g,
                 const short* __restrict__ VT_g, const int* __restrict__ vlen_p,
                 short* __restrict__ AOh)
{
    __shared__ short smem[16384];   // Kb[2][4096] | Vb[2][4096]
    short* Kb = smem;
    short* Vb = smem + 8192;

    const int t = threadIdx.x, w = t >> 6, l = t & 63;
    const int lh = l >> 5, lq = l & 31;

    const int lin = blockIdx.x;
    const int pair = (lin & 7) * 8 + (lin >> 7);
    const int qt = (lin >> 3) & 15;
    const int hd = pair & 15, b = pair >> 4;
    const int q0 = qt * 128;
    const int vlen = vlen_p[b];

    const short* Vbh = VT_g + (size_t)((b * NH + hd) * HDIM) * NS;

    // ===== fast path: whole 128-row block masked -> out rows = mean(V) =====
    if (q0 >= vlen) {
        float* fs = (float*)smem;
        const int d = t & 63, pc = t >> 6;
        const short* vrow = Vbh + (size_t)d * NS + pc * 512;
        float s = 0.f;
#pragma unroll 8
        for (int c = 0; c < 64; ++c) {
            short8 v = *(const short8*)(vrow + c * 8);
            float ps = 0.f;
#pragma unroll
            for (int j = 0; j < 8; ++j) ps += bf2f(v[j]);
            s += ps;
        }
        fs[pc * 64 + d] = s;
        __syncthreads();
        float* mv = fs + 256;
        if (t < 64)
            mv[t] = (fs[t] + fs[64 + t] + fs[128 + t] + fs[192 + t]) * (1.0f / 2048.0f);
        __syncthreads();

        const int row = t >> 1, hf = t & 1;
        const size_t base = ((size_t)b * NS + q0 + row) * ND + hd * HDIM;
        const int swz = (row & 7) << 3;
#pragma unroll
        for (int ch = 0; ch < 4; ++ch) {
            const int c0 = hf * 32 + ch * 8;
            short8 hv;
#pragma unroll
            for (int j = 0; j < 8; ++j) hv[j] = bf16rne(mv[c0 + j]);
            *(short8*)(AOh + base + (c0 ^ swz)) = hv;
        }
        return;
    }

    // ===== normal path =====
    short8 qf[4];
    {
        const int qrow = q0 + w * 32 + lq;
        const size_t base = ((size_t)(b * NS) + qrow) * ND + hd * HDIM;
#pragma unroll
        for (int d = 0; d < 4; ++d)
            qf[d] = *(const short8*)(Qh_g + base + d * 16 + 8 * lh);
        if (qrow >= vlen) {
#pragma unroll
            for (int d = 0; d < 4; ++d)
#pragma unroll
                for (int j = 0; j < 8; ++j) qf[d][j] = 0;
        }
    }

    const int lrow = l >> 3, lcol = (l & 7) * 8;
    const int csw = lcol ^ (lrow << 3);
    const short* Ksrc = Kh_g + ((size_t)(b * NS) + w * 16 + lrow) * ND + hd * HDIM + csw;
    short* Kd = Kb + w * 16 * 64;

    const int vrow = w * 16 + lrow;
    const short* VsrcR = Vbh + (size_t)vrow * NS + lcol;
    const int vdst = vrow * 64 + (lcol ^ ((lrow & 7) << 3));

    float lsum = 0.f;
    f32x16 o0, o1;
#pragma unroll
    for (int i = 0; i < 16; ++i) { o0[i] = 0.f; o1[i] = 0.f; }

    gl_lds16(Ksrc, Kd);
    gl_lds16(Ksrc + 8 * ND, Kd + 512);
    {
        short8 a = *(const short8*)(VsrcR);
        short8 c = *(const short8*)(VsrcR + 8 * NS);
        *(short8*)&Vb[vdst] = a;
        *(short8*)&Vb[vdst + 512] = c;
    }

    const int r7s = (lq & 7) << 3;

    for (int kt = 0; kt < NS / 64; ++kt) {
        const int cur = kt & 1;
        __syncthreads();

        short8 vn0, vn1;
        const bool pf = (kt < NS / 64 - 1);
        if (pf) {
            const short* s_ = Ksrc + (size_t)(kt + 1) * 64 * ND;
            short* d_ = Kd + (cur ^ 1) * 4096;
            gl_lds16(s_, d_);
            gl_lds16(s_ + 8 * ND, d_ + 512);
            vn0 = *(const short8*)(VsrcR + (kt + 1) * 64);
            vn1 = *(const short8*)(VsrcR + (kt + 1) * 64 + 8 * NS);
        }

#pragma unroll
        for (int kb = 0; kb < 2; ++kb) {
            const int rbase = cur * 4096 + (kb * 32 + lq) * 64;
            short8 kf0 = *(const short8*)&Kb[rbase + ((0  + 8 * lh) ^ r7s)];
            short8 kf1 = *(const short8*)&Kb[rbase + ((16 + 8 * lh) ^ r7s)];
            short8 kf2 = *(const short8*)&Kb[rbase + ((32 + 8 * lh) ^ r7s)];
            short8 kf3 = *(const short8*)&Kb[rbase + ((48 + 8 * lh) ^ r7s)];

            const int vb0 = cur * 4096 + lq * 64;
            const int vb1 = cur * 4096 + (32 + lq) * 64;
            short8 v00 = *(const short8*)&Vb[vb0 + ((kb * 32 + 8 * lh) ^ r7s)];
            short8 v01 = *(const short8*)&Vb[vb0 + ((kb * 32 + 16 + 8 * lh) ^ r7s)];
            short8 v10 = *(const short8*)&Vb[vb1 + ((kb * 32 + 8 * lh) ^ r7s)];
            short8 v11 = *(const short8*)&Vb[vb1 + ((kb * 32 + 16 + 8 * lh) ^ r7s)];

            f32x16 acc;
#pragma unroll
            for (int i = 0; i < 16; ++i) acc[i] = 0.f;
            __builtin_amdgcn_s_setprio(1);
            acc = __builtin_amdgcn_mfma_f32_32x32x16_bf16(kf0, qf[0], acc, 0, 0, 0);
            acc = __builtin_amdgcn_mfma_f32_32x32x16_bf16(kf1, qf[1], acc, 0, 0, 0);
            acc = __builtin_amdgcn_mfma_f32_32x32x16_bf16(kf2, qf[2], acc, 0, 0, 0);
            acc = __builtin_amdgcn_mfma_f32_32x32x16_bf16(kf3, qf[3], acc, 0, 0, 0);
            __builtin_amdgcn_s_setprio(0);

            float e[16];
#pragma unroll
            for (int i = 0; i < 16; ++i) e[i] = fexp2(acc[i]);
            float s4 = 0.f;
#pragma unroll
            for (int i = 0; i < 16; ++i) s4 += e[i];
            lsum += s4;

            unsigned d0 = cvtpk(e[0],  e[1]);
            unsigned d1 = cvtpk(e[2],  e[3]);
            unsigned d2 = cvtpk(e[4],  e[5]);
            unsigned d3 = cvtpk(e[6],  e[7]);
            unsigned d4 = cvtpk(e[8],  e[9]);
            unsigned d5 = cvtpk(e[10], e[11]);
            unsigned d6 = cvtpk(e[12], e[13]);
            unsigned d7 = cvtpk(e[14], e[15]);
            plswap(d0, d2);
            plswap(d1, d3);
            plswap(d4, d6);
            plswap(d5, d7);
            short8 B0 = mk8(d0, d1, d2, d3);
            short8 B1 = mk8(d4, d5, d6, d7);

            __builtin_amdgcn_s_setprio(1);
            o0 = __builtin_amdgcn_mfma_f32_32x32x16_bf16(v00, B0, o0, 0, 0, 0);
            o0 = __builtin_amdgcn_mfma_f32_32x32x16_bf16(v01, B1, o0, 0, 0, 0);
            o1 = __builtin_amdgcn_mfma_f32_32x32x16_bf16(v10, B0, o1, 0, 0, 0);
            o1 = __builtin_amdgcn_mfma_f32_32x32x16_bf16(v11, B1, o1, 0, 0, 0);
            __builtin_amdgcn_s_setprio(0);
        }

        if (pf) {
            *(short8*)&Vb[(cur ^ 1) * 4096 + vdst]       = vn0;
            *(short8*)&Vb[(cur ^ 1) * 4096 + vdst + 512] = vn1;
        }
    }

    const float lt = lsum + __shfl_xor(lsum, 32);
    const float rin = 1.0f / lt;

    __syncthreads();
    float* Ob = (float*)smem + w * 1152;
    const int qe = l >> 1, dp = l & 1;
    const size_t aorow = (size_t)b * NS + q0 + w * 32 + qe;
    const int r7e = (qe & 7) << 3;
#pragma unroll
    for (int dt = 0; dt < 2; ++dt) {
        const f32x16 ov = dt ? o1 : o0;
#pragma unroll
        for (int r = 0; r < 16; ++r)
            Ob[lq * 36 + (r & 3) + 8 * (r >> 2) + 4 * lh] = ov[r] * rin;
        float xv[16];
#pragma unroll
        for (int c = 0; c < 4; ++c) {
            float4 x = *(const float4*)&Ob[qe * 36 + dp * 16 + c * 4];
            xv[c * 4 + 0] = x.x; xv[c * 4 + 1] = x.y;
            xv[c * 4 + 2] = x.z; xv[c * 4 + 3] = x.w;
        }
        short8 hv0, hv1;
#pragma unroll
        for (int j = 0; j < 8; ++j) {
            hv0[j] = bf16rne(xv[j]);
            hv1[j] = bf16rne(xv[8 + j]);
        }
        const size_t base = aorow * ND + hd * HDIM;
        *(short8*)(AOh + base + ((dt * 32 + dp * 16 + 0) ^ r7e)) = hv0;
        *(short8*)(AOh + base + ((dt * 32 + dp * 16 + 8) ^ r7e)) = hv1;
    }
}

// ---------------------------------------------------------------------------
extern "C" void kernel_launch(void* const* d_in, const int* in_sizes, int n_in,
                              void* d_out, int out_size, void* d_ws, size_t ws_size,
                              hipStream_t stream)
{
    const float* queries = (const float*)d_in[0];
    const float* keys    = (const float*)d_in[1];
    const float* values  = (const float*)d_in[2];
    const int*   vlen    = (const int*)d_in[3];
    const float* Wq      = (const float*)d_in[4];
    const float* Wk      = (const float*)d_in[5];
    const float* Wv      = (const float*)d_in[6];
    const float* Wo      = (const float*)d_in[7];
    float* out           = (float*)d_out;

    // ws: A0,A1,A2 (3x16.8MB) | W4 (8MB) | Qhi,Khi,VT (3x16.8MB) = 108.7 MB
    short* A0  = (short*)d_ws;
    short* A1  = A0 + MN_FULL;
    short* A2  = A1 + MN_FULL;
    short* W4  = A2 + MN_FULL;
    short* Qhi = W4 + 4 * (size_t)ND * ND;
    short* Khi = Qhi + MN_FULL;
    short* VT  = Khi + MN_FULL;
    short* AOh = A0;   // reuse after projections

    const int gA = (int)(MN_FULL / 8 / 256);          // 4096
    const int gW = (int)((size_t)ND * ND / 8 / 256);  // 512
    dim3 gP(NM / 128, ND / 128);                      // (64, 8)
    dim3 gV(ND / 128, NM / 128);                      // (8, 64)

    const float QSCALE = 0.125f * 1.44269504089f;     // 1/sqrt(64) * log2(e)

    convA3<<<dim3(gA, 1, 3), 256, 0, stream>>>(queries, keys, values, A0, A1, A2);
    convW4<<<dim3(gW, 1, 4), 256, 0, stream>>>(Wq, Wk, Wv, Wo, W4);

    gemm1<3><<<gP, 256, 0, stream>>>(A0, W4,                         Qhi, nullptr, QSCALE);
    gemm1<3><<<gP, 256, 0, stream>>>(A1, W4 + (size_t)ND * ND,       Khi, nullptr, 1.0f);
    gemm1<2><<<gV, 256, 0, stream>>>(W4 + 2 * (size_t)ND * ND, A2,   VT,  nullptr, 1.0f);

    attn_mfma12<<<dim3(1024), 256, 0, stream>>>(Qhi, Khi, VT, vlen, AOh);

    gemm1<0><<<gP, 256, 0, stream>>>(AOh, W4 + 3 * (size_t)ND * ND, nullptr, out, 1.0f);
}

// Round 19
// 194.662 us; speedup vs baseline: 1.0393x; 1.0209x over previous
//
#include <hip/hip_runtime.h>
#include <hip/hip_bf16.h>

#define NB 4
#define NS 2048
#define ND 1024
#define NH 16
#define HDIM 64
#define NM (NB * NS)
#define MN_FULL ((size_t)NM * ND)

typedef short short8 __attribute__((ext_vector_type(8)));
typedef float f32x4 __attribute__((ext_vector_type(4)));
typedef float f32x16 __attribute__((ext_vector_type(16)));
typedef unsigned uint4v __attribute__((ext_vector_type(4)));

__device__ __forceinline__ short bf16rne(float f) {
    unsigned u = __builtin_bit_cast(unsigned, f);
    u += 0x7fff + ((u >> 16) & 1);
    return (short)(u >> 16);
}
__device__ __forceinline__ float bf2f(short s) {
    unsigned u = ((unsigned)(unsigned short)s) << 16;
    return __builtin_bit_cast(float, u);
}
__device__ __forceinline__ void gl_lds16(const short* g, short* l) {
    __builtin_amdgcn_global_load_lds(
        (const __attribute__((address_space(1))) void*)g,
        (__attribute__((address_space(3))) void*)l, 16, 0, 0);
}
__device__ __forceinline__ float fexp2(float x) {
#if __has_builtin(__builtin_amdgcn_exp2f)
    return __builtin_amdgcn_exp2f(x);
#else
    return exp2f(x);
#endif
}
__device__ __forceinline__ unsigned cvtpk(float a, float b) {
    unsigned d;
    asm("v_cvt_pk_bf16_f32 %0, %1, %2" : "=v"(d) : "v"(a), "v"(b));
    return d;
}
__device__ __forceinline__ void plswap(unsigned& x, unsigned& y) {
    asm("v_permlane32_swap_b32 %0, %1" : "+v"(x), "+v"(y));
}
__device__ __forceinline__ short8 mk8(unsigned a, unsigned b, unsigned c, unsigned d) {
    uint4v u = {a, b, c, d};
    return __builtin_bit_cast(short8, u);
}

// ---------------------------------------------------------------------------
// convA3: 3 tensors f32 [M,1024] -> bf16 hi, swizzled in k-64 by (m&7).
// ---------------------------------------------------------------------------
__global__ __launch_bounds__(256)
void convA3(const float* __restrict__ A0, const float* __restrict__ A1,
            const float* __restrict__ A2, short* __restrict__ D0,
            short* __restrict__ D1, short* __restrict__ D2)
{
    const int z = blockIdx.z;
    const float* A = (z == 0) ? A0 : (z == 1) ? A1 : A2;
    short* D = (z == 0) ? D0 : (z == 1) ? D1 : D2;

    const size_t idx = (size_t)blockIdx.x * 256 + threadIdx.x;
    const int m = (int)(idx >> 7);
    const int k = (int)((idx & 127) << 3);
    const float* src = A + ((size_t)m << 10) + k;
    float4 x0 = *(const float4*)src;
    float4 x1 = *(const float4*)(src + 4);
    float xv[8] = {x0.x, x0.y, x0.z, x0.w, x1.x, x1.y, x1.z, x1.w};
    short8 hv;
#pragma unroll
    for (int j = 0; j < 8; ++j) hv[j] = bf16rne(xv[j]);
    const int ksw = (k & ~63) | ((k & 63) ^ ((m & 7) << 3));
    *(short8*)(D + ((size_t)m << 10) + ksw) = hv;
}

// ---------------------------------------------------------------------------
// convW4: 4 weights f32 W[k][n] -> W^T bf16 [n][k], swizzled by (n&7).
// ---------------------------------------------------------------------------
__global__ __launch_bounds__(256)
void convW4(const float* __restrict__ W0, const float* __restrict__ W1,
            const float* __restrict__ W2, const float* __restrict__ W3,
            short* __restrict__ Wb)
{
    const int z = blockIdx.z;
    const float* W = (z == 0) ? W0 : (z == 1) ? W1 : (z == 2) ? W2 : W3;
    short* Wh = Wb + (size_t)z * ND * ND;

    const int idx = blockIdx.x * 256 + threadIdx.x;
    const int n = idx & 1023;
    const int k = (idx >> 10) << 3;
    short8 hv;
#pragma unroll
    for (int j = 0; j < 8; ++j) hv[j] = bf16rne(W[(size_t)(k + j) * ND + n]);
    const int ksw = (k & ~63) | ((k & 63) ^ ((n & 7) << 3));
    *(short8*)(Wh + ((size_t)n << 10) + ksw) = hv;
}

// ---------------------------------------------------------------------------
// Single-bf16 MFMA GEMM (R16 proven): D[row][col] = sum_k A[row][k]*B[col][k].
// EPI 0: f32 out. EPI 3: bf16 out (scale). EPI 2: VT out.
// vlen_p != nullptr (Q projection only): skip blocks whose entire 128-row
// tile is masked (q >= vlen[b]) — output never consumed by attention.
// ---------------------------------------------------------------------------
template <int EPI>
__global__ __launch_bounds__(256, 3)
void gemm1(const short* __restrict__ Ah, const short* __restrict__ Bh,
           short* __restrict__ D1, float* __restrict__ Cf, float scale,
           const int* __restrict__ vlen_p)
{
    __shared__ short lds[16384];
    short* AhS = lds;
    short* BhS = lds + 8192;

    const size_t bm = (size_t)blockIdx.x * 128, bn = (size_t)blockIdx.y * 128;
    if (EPI == 3 && vlen_p != nullptr) {
        if ((int)(bm & (NS - 1)) >= vlen_p[bm >> 11]) return;   // tile fully masked
    }

    const int t = threadIdx.x, w = t >> 6, l = t & 63;
    const int g = l >> 4, li = l & 15;
    const int wr = w >> 1, wc = w & 1;

    f32x4 acc[4][4];
#pragma unroll
    for (int i = 0; i < 4; ++i)
#pragma unroll
        for (int j = 0; j < 4; ++j) acc[i][j] = (f32x4){0.f, 0.f, 0.f, 0.f};

    const int srow = w * 32 + (l >> 3);
    const int schk = (l & 7) << 3;
    const short* pAh = Ah + (bm + srow) * 1024 + schk;
    const short* pBh = Bh + (bn + srow) * 1024 + schk;
    const int lbase = w * 32 * 64;

    for (int kt = 0; kt < 16; ++kt) {
        const int k0 = kt * 64;
        __syncthreads();
#pragma unroll
        for (int r = 0; r < 4; ++r) {
            const int go = r * 8 * 1024 + k0;
            const int lo_ = lbase + r * 512;
            gl_lds16(pAh + go, AhS + lo_);
            gl_lds16(pBh + go, BhS + lo_);
        }
        __syncthreads();
#pragma unroll
        for (int ks = 0; ks < 2; ++ks) {
            short8 fah[4], fbh[4];
#pragma unroll
            for (int i = 0; i < 4; ++i) {
                const int m = wr * 64 + i * 16 + li;
                const int c = (ks * 32 + g * 8) ^ ((m & 7) << 3);
                fah[i] = *(const short8*)&AhS[m * 64 + c];
                const int n = wc * 64 + i * 16 + li;
                const int cn = (ks * 32 + g * 8) ^ ((n & 7) << 3);
                fbh[i] = *(const short8*)&BhS[n * 64 + cn];
            }
#pragma unroll
            for (int i = 0; i < 4; ++i)
#pragma unroll
                for (int j = 0; j < 4; ++j)
                    acc[i][j] = __builtin_amdgcn_mfma_f32_16x16x32_bf16(fah[i], fbh[j], acc[i][j], 0, 0, 0);
        }
    }

    __syncthreads();
    float* Ofs = (float*)lds + w * 2048;
#pragma unroll
    for (int half = 0; half < 2; ++half) {
#pragma unroll
        for (int i = 0; i < 4; ++i)
#pragma unroll
            for (int jj = 0; jj < 2; ++jj)
#pragma unroll
                for (int r = 0; r < 4; ++r)
                    Ofs[(i * 16 + g * 4 + r) * 32 + jj * 16 + li] = acc[i][half * 2 + jj][r];
        // same-wave in-order LDS: reads below see writes above
        if (EPI == 3) {
#pragma unroll
            for (int rr = 0; rr < 2; ++rr) {
                const int row = rr * 32 + (l >> 1);
                const int coff = (l & 1) * 16;
                const float* src = &Ofs[row * 32 + coff];
                short8 h0, h1;
#pragma unroll
                for (int jj = 0; jj < 8; ++jj) {
                    h0[jj] = bf16rne(src[jj] * scale);
                    h1[jj] = bf16rne(src[8 + jj] * scale);
                }
                const size_t rg = bm + wr * 64 + row;
                const size_t cg = bn + wc * 64 + half * 32 + coff;
                *(short8*)(D1 + rg * 1024 + cg)     = h0;
                *(short8*)(D1 + rg * 1024 + cg + 8) = h1;
            }
        } else if (EPI == 0) {
#pragma unroll
            for (int rr = 0; rr < 2; ++rr) {
                const int row = rr * 32 + (l >> 1);
                const int coff = (l & 1) * 16;
                const float* src = &Ofs[row * 32 + coff];
                const size_t rg = bm + wr * 64 + row;
                const size_t cg = bn + wc * 64 + half * 32 + coff;
#pragma unroll
                for (int q = 0; q < 4; ++q)
                    *(float4*)(Cf + rg * 1024 + cg + q * 4) = *(const float4*)(src + q * 4);
            }
        } else {   // EPI == 2: VT[b][h][d][s]
#pragma unroll
            for (int p = 0; p < 4; ++p) {
                const int nl = p * 16 + (l >> 2);
                const int mc = (l & 3) * 8;
                const float* src = &Ofs[nl * 32 + mc];
                short8 v;
#pragma unroll
                for (int jj = 0; jj < 8; ++jj) v[jj] = bf16rne(src[jj]);
                const int ng = (int)bm + wr * 64 + nl;
                const size_t mg = bn + wc * 64 + half * 32 + mc;
                const int h_ = ng >> 6, d_ = ng & 63;
                const int b_ = (int)(mg >> 11), s_ = (int)(mg & 2047);
                *(short8*)(D1 + (((size_t)(b_ * NH + h_) * HDIM + d_) << 11) + s_) = v;
            }
        }
    }
}

// ---------------------------------------------------------------------------
// MFMA flash attention v11 (R16, proven 76 us): K via gl_lds dbuf, V via
// reg-staging with write-addr swizzle, in-register P (cvt_pk + permlane),
// no max-tracking, masked-block fast path, XCD decode. grid=1024 x 256.
// ---------------------------------------------------------------------------
__global__ __launch_bounds__(256, 4)
void attn_mfma11(const short* __restrict__ Qh_g, const short* __restrict__ Kh_g,
                 const short* __restrict__ VT_g, const int* __restrict__ vlen_p,
                 short* __restrict__ AOh)
{
    __shared__ short smem[16384];   // Kb[2][4096] | Vb[2][4096]
    short* Kb = smem;
    short* Vb = smem + 8192;

    const int t = threadIdx.x, w = t >> 6, l = t & 63;
    const int lh = l >> 5, lq = l & 31;

    const int lin = blockIdx.x;
    const int pair = (lin & 7) * 8 + (lin >> 7);
    const int qt = (lin >> 3) & 15;
    const int hd = pair & 15, b = pair >> 4;
    const int q0 = qt * 128;
    const int vlen = vlen_p[b];

    const short* Vbh = VT_g + (size_t)((b * NH + hd) * HDIM) * NS;

    // ===== fast path: whole 128-row block masked -> out rows = mean(V) =====
    if (q0 >= vlen) {
        float* fs = (float*)smem;
        const int d = t & 63, pc = t >> 6;
        const short* vrow = Vbh + (size_t)d * NS + pc * 512;
        float s = 0.f;
#pragma unroll 8
        for (int c = 0; c < 64; ++c) {
            short8 v = *(const short8*)(vrow + c * 8);
            float ps = 0.f;
#pragma unroll
            for (int j = 0; j < 8; ++j) ps += bf2f(v[j]);
            s += ps;
        }
        fs[pc * 64 + d] = s;
        __syncthreads();
        float* mv = fs + 256;
        if (t < 64)
            mv[t] = (fs[t] + fs[64 + t] + fs[128 + t] + fs[192 + t]) * (1.0f / 2048.0f);
        __syncthreads();

        const int row = t >> 1, hf = t & 1;
        const size_t base = ((size_t)b * NS + q0 + row) * ND + hd * HDIM;
        const int swz = (row & 7) << 3;
#pragma unroll
        for (int ch = 0; ch < 4; ++ch) {
            const int c0 = hf * 32 + ch * 8;
            short8 hv;
#pragma unroll
            for (int j = 0; j < 8; ++j) hv[j] = bf16rne(mv[c0 + j]);
            *(short8*)(AOh + base + (c0 ^ swz)) = hv;
        }
        return;
    }

    // ===== normal path =====
    short8 qf[4];
    {
        const int qrow = q0 + w * 32 + lq;
        const size_t base = ((size_t)(b * NS) + qrow) * ND + hd * HDIM;
#pragma unroll
        for (int d = 0; d < 4; ++d)
            qf[d] = *(const short8*)(Qh_g + base + d * 16 + 8 * lh);
        if (qrow >= vlen) {
#pragma unroll
            for (int d = 0; d < 4; ++d)
#pragma unroll
                for (int j = 0; j < 8; ++j) qf[d][j] = 0;
        }
    }

    const int lrow = l >> 3, lcol = (l & 7) * 8;
    const int csw = lcol ^ (lrow << 3);
    const short* Ksrc = Kh_g + ((size_t)(b * NS) + w * 16 + lrow) * ND + hd * HDIM + csw;
    short* Kd = Kb + w * 16 * 64;

    const int vrow = w * 16 + lrow;
    const short* VsrcR = Vbh + (size_t)vrow * NS + lcol;
    const int vdst = vrow * 64 + (lcol ^ ((lrow & 7) << 3));

    float lsum = 0.f;
    f32x16 o0, o1;
#pragma unroll
    for (int i = 0; i < 16; ++i) { o0[i] = 0.f; o1[i] = 0.f; }

    gl_lds16(Ksrc, Kd);
    gl_lds16(Ksrc + 8 * ND, Kd + 512);
    {
        short8 a = *(const short8*)(VsrcR);
        short8 c = *(const short8*)(VsrcR + 8 * NS);
        *(short8*)&Vb[vdst] = a;
        *(short8*)&Vb[vdst + 512] = c;
    }

    const int r7s = (lq & 7) << 3;

    for (int kt = 0; kt < NS / 64; ++kt) {
        const int cur = kt & 1;
        __syncthreads();

        short8 vn0, vn1;
        const bool pf = (kt < NS / 64 - 1);
        if (pf) {
            const short* s_ = Ksrc + (size_t)(kt + 1) * 64 * ND;
            short* d_ = Kd + (cur ^ 1) * 4096;
            gl_lds16(s_, d_);
            gl_lds16(s_ + 8 * ND, d_ + 512);
            vn0 = *(const short8*)(VsrcR + (kt + 1) * 64);
            vn1 = *(const short8*)(VsrcR + (kt + 1) * 64 + 8 * NS);
        }

#pragma unroll
        for (int kb = 0; kb < 2; ++kb) {
            const int rbase = cur * 4096 + (kb * 32 + lq) * 64;
            short8 kf0 = *(const short8*)&Kb[rbase + ((0  + 8 * lh) ^ r7s)];
            short8 kf1 = *(const short8*)&Kb[rbase + ((16 + 8 * lh) ^ r7s)];
            short8 kf2 = *(const short8*)&Kb[rbase + ((32 + 8 * lh) ^ r7s)];
            short8 kf3 = *(const short8*)&Kb[rbase + ((48 + 8 * lh) ^ r7s)];

            const int vb0 = cur * 4096 + lq * 64;
            const int vb1 = cur * 4096 + (32 + lq) * 64;
            short8 v00 = *(const short8*)&Vb[vb0 + ((kb * 32 + 8 * lh) ^ r7s)];
            short8 v01 = *(const short8*)&Vb[vb0 + ((kb * 32 + 16 + 8 * lh) ^ r7s)];
            short8 v10 = *(const short8*)&Vb[vb1 + ((kb * 32 + 8 * lh) ^ r7s)];
            short8 v11 = *(const short8*)&Vb[vb1 + ((kb * 32 + 16 + 8 * lh) ^ r7s)];

            f32x16 acc;
#pragma unroll
            for (int i = 0; i < 16; ++i) acc[i] = 0.f;
            acc = __builtin_amdgcn_mfma_f32_32x32x16_bf16(kf0, qf[0], acc, 0, 0, 0);
            acc = __builtin_amdgcn_mfma_f32_32x32x16_bf16(kf1, qf[1], acc, 0, 0, 0);
            acc = __builtin_amdgcn_mfma_f32_32x32x16_bf16(kf2, qf[2], acc, 0, 0, 0);
            acc = __builtin_amdgcn_mfma_f32_32x32x16_bf16(kf3, qf[3], acc, 0, 0, 0);

            float e[16];
#pragma unroll
            for (int i = 0; i < 16; ++i) e[i] = fexp2(acc[i]);
            float s4 = 0.f;
#pragma unroll
            for (int i = 0; i < 16; ++i) s4 += e[i];
            lsum += s4;

            unsigned d0 = cvtpk(e[0],  e[1]);
            unsigned d1 = cvtpk(e[2],  e[3]);
            unsigned d2 = cvtpk(e[4],  e[5]);
            unsigned d3 = cvtpk(e[6],  e[7]);
            unsigned d4 = cvtpk(e[8],  e[9]);
            unsigned d5 = cvtpk(e[10], e[11]);
            unsigned d6 = cvtpk(e[12], e[13]);
            unsigned d7 = cvtpk(e[14], e[15]);
            plswap(d0, d2);
            plswap(d1, d3);
            plswap(d4, d6);
            plswap(d5, d7);
            short8 B0 = mk8(d0, d1, d2, d3);
            short8 B1 = mk8(d4, d5, d6, d7);

            o0 = __builtin_amdgcn_mfma_f32_32x32x16_bf16(v00, B0, o0, 0, 0, 0);
            o0 = __builtin_amdgcn_mfma_f32_32x32x16_bf16(v01, B1, o0, 0, 0, 0);
            o1 = __builtin_amdgcn_mfma_f32_32x32x16_bf16(v10, B0, o1, 0, 0, 0);
            o1 = __builtin_amdgcn_mfma_f32_32x32x16_bf16(v11, B1, o1, 0, 0, 0);
        }

        if (pf) {
            *(short8*)&Vb[(cur ^ 1) * 4096 + vdst]       = vn0;
            *(short8*)&Vb[(cur ^ 1) * 4096 + vdst + 512] = vn1;
        }
    }

    const float lt = lsum + __shfl_xor(lsum, 32);
    const float rin = 1.0f / lt;

    __syncthreads();
    float* Ob = (float*)smem + w * 1152;
    const int qe = l >> 1, dp = l & 1;
    const size_t aorow = (size_t)b * NS + q0 + w * 32 + qe;
    const int r7e = (qe & 7) << 3;
#pragma unroll
    for (int dt = 0; dt < 2; ++dt) {
        const f32x16 ov = dt ? o1 : o0;
#pragma unroll
        for (int r = 0; r < 16; ++r)
            Ob[lq * 36 + (r & 3) + 8 * (r >> 2) + 4 * lh] = ov[r] * rin;
        float xv[16];
#pragma unroll
        for (int c = 0; c < 4; ++c) {
            float4 x = *(const float4*)&Ob[qe * 36 + dp * 16 + c * 4];
            xv[c * 4 + 0] = x.x; xv[c * 4 + 1] = x.y;
            xv[c * 4 + 2] = x.z; xv[c * 4 + 3] = x.w;
        }
        short8 hv0, hv1;
#pragma unroll
        for (int j = 0; j < 8; ++j) {
            hv0[j] = bf16rne(xv[j]);
            hv1[j] = bf16rne(xv[8 + j]);
        }
        const size_t base = aorow * ND + hd * HDIM;
        *(short8*)(AOh + base + ((dt * 32 + dp * 16 + 0) ^ r7e)) = hv0;
        *(short8*)(AOh + base + ((dt * 32 + dp * 16 + 8) ^ r7e)) = hv1;
    }
}

// ---------------------------------------------------------------------------
extern "C" void kernel_launch(void* const* d_in, const int* in_sizes, int n_in,
                              void* d_out, int out_size, void* d_ws, size_t ws_size,
                              hipStream_t stream)
{
    const float* queries = (const float*)d_in[0];
    const float* keys    = (const float*)d_in[1];
    const float* values  = (const float*)d_in[2];
    const int*   vlen    = (const int*)d_in[3];
    const float* Wq      = (const float*)d_in[4];
    const float* Wk      = (const float*)d_in[5];
    const float* Wv      = (const float*)d_in[6];
    const float* Wo      = (const float*)d_in[7];
    float* out           = (float*)d_out;

    // ws: A0,A1,A2 (3x16.8MB) | W4 (8MB) | Qhi,Khi,VT (3x16.8MB) = 108.7 MB
    short* A0  = (short*)d_ws;
    short* A1  = A0 + MN_FULL;
    short* A2  = A1 + MN_FULL;
    short* W4  = A2 + MN_FULL;
    short* Qhi = W4 + 4 * (size_t)ND * ND;
    short* Khi = Qhi + MN_FULL;
    short* VT  = Khi + MN_FULL;
    short* AOh = A0;   // reuse after projections

    const int gA = (int)(MN_FULL / 8 / 256);          // 4096
    const int gW = (int)((size_t)ND * ND / 8 / 256);  // 512
    dim3 gP(NM / 128, ND / 128);                      // (64, 8)
    dim3 gV(ND / 128, NM / 128);                      // (8, 64)

    const float QSCALE = 0.125f * 1.44269504089f;     // 1/sqrt(64) * log2(e)

    convA3<<<dim3(gA, 1, 3), 256, 0, stream>>>(queries, keys, values, A0, A1, A2);
    convW4<<<dim3(gW, 1, 4), 256, 0, stream>>>(Wq, Wk, Wv, Wo, W4);

    // Q projection: blocks whose 128-row tile is fully masked are skipped
    gemm1<3><<<gP, 256, 0, stream>>>(A0, W4,                         Qhi, nullptr, QSCALE, vlen);
    gemm1<3><<<gP, 256, 0, stream>>>(A1, W4 + (size_t)ND * ND,       Khi, nullptr, 1.0f, nullptr);
    gemm1<2><<<gV, 256, 0, stream>>>(W4 + 2 * (size_t)ND * ND, A2,   VT,  nullptr, 1.0f, nullptr);

    attn_mfma11<<<dim3(1024), 256, 0, stream>>>(Qhi, Khi, VT, vlen, AOh);

    gemm1<0><<<gP, 256, 0, stream>>>(AOh, W4 + 3 * (size_t)ND * ND, nullptr, out, 1.0f, nullptr);
}